// Round 7
// baseline (1298.885 us; speedup 1.0000x reference)
//
#include <hip/hip_runtime.h>
#include <math.h>

#define BB    8
#define CC    64
#define NN    256
#define MM    20      // retained modes per axis
#define NKK   40      // retained row-modes: {0..19} U {236..255}
#define NLAY  3
#define FCD   128
#define PLANE (NN*NN)

// Fast tanh: clamp + exp-based. v_exp_f32/v_rcp_f32, ~1e-7 abs error, no branches.
__device__ __forceinline__ float fast_tanh(float x) {
    float xc = fminf(fmaxf(x, -15.f), 15.f);
    float e = __expf(2.f * xc);
    return (e - 1.f) / (e + 1.f);
}

// ---------------------------------------------------------------------------
// Basis precompute (double precision on device; tiny).
__global__ __launch_bounds__(256) void k_basis(float* __restrict__ FlT, float* __restrict__ FkT,
                                               float* __restrict__ BkT, float* __restrict__ BlT,
                                               float* __restrict__ CwT, const float* __restrict__ conv_w) {
    int t = threadIdx.x;
    const double PI = 3.14159265358979323846;
    for (int j = t; j < NN*MM; j += 256) {
        int y = j / MM, l = j % MM;
        double g = (y == 0 || y == NN-1) ? 1.0 : 2.0;
        FlT[j] = (float)(g * cos(PI * (double)(l*y) / (double)(NN-1)));
    }
    for (int j = t; j < NN*NKK; j += 256) {
        int x = j / NKK, k = j % NKK;
        int rk = (k < MM) ? k : (NN - NKK + k);
        double g = (x == 0 || x == NN-1) ? 1.0 : 2.0;
        FkT[j] = (float)(g * cos(PI * (double)(rk*x) / (double)(NN-1)));
    }
    for (int j = t; j < NKK*NN; j += 256) {
        int k = j / NN, p = j % NN;
        int rk = (k < MM) ? k : (NN - NKK + k);
        double g = (rk == 0 || rk == NN-1) ? 1.0 : 2.0;
        BkT[j] = (float)(g * cos(PI * (double)(rk*p) / (double)(NN-1)));
    }
    for (int j = t; j < MM*NN; j += 256) {
        int l = j / NN, q = j % NN;
        double g = (l == 0) ? 1.0 : 2.0;
        BlT[j] = (float)(g * cos(PI * (double)(q*l) / (double)(NN-1)));
    }
    for (int j = t; j < NLAY*CC*CC; j += 256) {
        int lay = j / (CC*CC), r = j % (CC*CC);
        int i = r / CC, o = r % CC;
        CwT[j] = conv_w[lay*CC*CC + o*CC + i];
    }
}

// ---------------------------------------------------------------------------
// fc0: h[b,c,p,q] = sum_d x[b,p,q,d]*w[d,c] + bias[c].  Block=(b,p), thread=q.
__global__ __launch_bounds__(256) void k_fc0(const float* __restrict__ xin, const float* __restrict__ w,
                                             const float* __restrict__ bias, float* __restrict__ h) {
    __shared__ float xs[NN*3];
    int b = blockIdx.x >> 8, p = blockIdx.x & 255, q = threadIdx.x;
    size_t rowbase = ((size_t)(b*NN + p)*NN) * 3;
    for (int j = q; j < NN*3; j += 256) xs[j] = xin[rowbase + j];
    __syncthreads();
    float v0 = xs[q*3+0], v1 = xs[q*3+1], v2 = xs[q*3+2];
    size_t obase = (size_t)b*CC*PLANE + (size_t)p*NN + q;
    #pragma unroll 8
    for (int c = 0; c < CC; ++c) {
        float hv = bias[c] + v0*w[c] + v1*w[CC+c] + v2*w[2*CC+c];
        h[obase + (size_t)c*PLANE] = hv;
    }
}

// ---------------------------------------------------------------------------
// Forward truncated DCT: per (b,c) plane, G[k,l] = Fk @ h @ FlT.
__global__ __launch_bounds__(256, 2) void k_fwd(const float* __restrict__ h, const float* __restrict__ FkT,
                                                const float* __restrict__ FlT, float* __restrict__ Gt) {
    __shared__ float P[NKK][NN+1];
    int plane = blockIdx.x;                 // b*CC + c
    int t = threadIdx.x;
    const float* hp = h + (size_t)plane * PLANE;
    float acc[NKK];
    #pragma unroll
    for (int k = 0; k < NKK; ++k) acc[k] = 0.f;
    #pragma unroll 2
    for (int x = 0; x < NN; ++x) {
        float hv = hp[x*NN + t];
        const float* fr = &FkT[x*NKK];      // wave-uniform address -> s_load
        #pragma unroll
        for (int k = 0; k < NKK; ++k) acc[k] += fr[k] * hv;
    }
    #pragma unroll
    for (int k = 0; k < NKK; ++k) P[k][t] = acc[k];
    __syncthreads();
    int b = plane >> 6, c = plane & 63;
    for (int j = t; j < NKK*MM; j += 256) {
        int k = j / MM, l = j % MM;
        float a = 0.f;
        for (int y = 0; y < NN; ++y) a += P[k][y] * FlT[y*MM + l];
        Gt[((size_t)(k*BB + b)*CC + c)*MM + l] = a;
    }
}

// ---------------------------------------------------------------------------
// Spectral mode-mix: S[b,k,l,o] = sum_i G[b,i,kb,l] * w[i,o,kk,l].
// S layout now [b][k][l][o] (o contiguous) so downstream reads are
// coalesced vector loads (k_inv1) / wave-uniform scalar rows (k_combine via U).
__global__ __launch_bounds__(256, 2) void k_spec(const float* __restrict__ Gt, const float* __restrict__ w1,
                                                 const float* __restrict__ w2, float* __restrict__ S) {
    extern __shared__ float gl[];           // BB*CC*MM = 10240 floats ([b][c][l] order)
    int kb = blockIdx.x;
    int t = threadIdx.x;
    const float* chunk = Gt + (size_t)kb * (BB*CC*MM);
    for (int j = t; j < BB*CC*MM; j += 256) gl[j] = chunk[j];
    __syncthreads();
    int o = t & 63, g = t >> 6;
    int b0 = 2*g, b1 = 2*g + 1;
    const float* wp; int kk;
    if (kb < MM) { wp = w1; kk = kb; } else { wp = w2; kk = kb - MM; }
    float a0[MM], a1[MM];
    #pragma unroll
    for (int l = 0; l < MM; ++l) { a0[l] = 0.f; a1[l] = 0.f; }
    for (int i = 0; i < CC; ++i) {
        const float4* wr4 = reinterpret_cast<const float4*>(wp + ((size_t)(i*CC + o)*MM + kk)*MM);
        const float4* g04 = reinterpret_cast<const float4*>(&gl[(b0*CC + i)*MM]);
        const float4* g14 = reinterpret_cast<const float4*>(&gl[(b1*CC + i)*MM]);
        #pragma unroll
        for (int l4 = 0; l4 < MM/4; ++l4) {
            float4 wv = wr4[l4];
            float4 gv0 = g04[l4];
            float4 gv1 = g14[l4];
            a0[4*l4+0] += wv.x*gv0.x; a0[4*l4+1] += wv.y*gv0.y;
            a0[4*l4+2] += wv.z*gv0.z; a0[4*l4+3] += wv.w*gv0.w;
            a1[4*l4+0] += wv.x*gv1.x; a1[4*l4+1] += wv.y*gv1.y;
            a1[4*l4+2] += wv.z*gv1.z; a1[4*l4+3] += wv.w*gv1.w;
        }
    }
    #pragma unroll
    for (int l = 0; l < MM; ++l) {
        S[((size_t)(b0*NKK + kb)*MM + l)*CC + o] = a0[l];   // coalesced in o
        S[((size_t)(b1*NKK + kb)*MM + l)*CC + o] = a1[l];
    }
}

// ---------------------------------------------------------------------------
// Inverse stage 1: U[b,p,l,o] = sum_k BkT[k,p] * S[b,k,l,o].
// Block=(b,p) (2048 blocks); wave w handles l = w + 4j (j=0..4); lane = o.
// BkT[k,p] wave-uniform -> s_load; S rows coalesced; no LDS.
__global__ __launch_bounds__(256, 2) void k_inv1(const float* __restrict__ S, const float* __restrict__ BkT,
                                                 float* __restrict__ U) {
    int b = blockIdx.x >> 8, p = blockIdx.x & 255;
    int o = threadIdx.x & 63, w = threadIdx.x >> 6;
    float acc[5];
    #pragma unroll
    for (int j = 0; j < 5; ++j) acc[j] = 0.f;
    for (int k = 0; k < NKK; ++k) {
        float bk = BkT[k*NN + p];                       // wave-uniform
        const float* sb = S + ((size_t)(b*NKK + k)*MM + w)*CC + o;
        #pragma unroll
        for (int j = 0; j < 5; ++j) acc[j] += bk * sb[(size_t)(4*j)*CC];
    }
    float* ub = U + ((size_t)(b*NN + p)*MM + w)*CC + o;
    #pragma unroll
    for (int j = 0; j < 5; ++j) ub[(size_t)(4*j)*CC] = acc[j];
}

// ---------------------------------------------------------------------------
// Combine IN PLACE, 2 rows (p0,p0+1) per block, NO LDS:
//   h[b,o,p,q] = tanh( conv(h)[o] + cb[o] + sum_l U[b,p,l,o]*BlT[l,q] )
// All weight/U reads are wave-uniform -> scalar pipe; acc constant-indexed.
__global__ __launch_bounds__(256, 2) void k_combine(float* h, const float* __restrict__ U,
                                                    const float* __restrict__ BlT, const float* __restrict__ cwt,
                                                    const float* __restrict__ cb) {
    int b = blockIdx.x >> 7, p2 = blockIdx.x & 127;
    int p0 = 2*p2, q = threadIdx.x;
    float acc0[CC], acc1[CC];
    #pragma unroll
    for (int o = 0; o < CC; ++o) { float cv = cb[o]; acc0[o] = cv; acc1[o] = cv; }
    float* hb = h + (size_t)b*CC*PLANE + (size_t)p0*NN + q;
    #pragma unroll 4
    for (int i = 0; i < CC; ++i) {
        float hv0 = hb[(size_t)i*PLANE];
        float hv1 = hb[(size_t)i*PLANE + NN];
        const float* wr = &cwt[i*CC];                   // wave-uniform -> s_load
        #pragma unroll
        for (int o = 0; o < CC; ++o) { acc0[o] += wr[o]*hv0; acc1[o] += wr[o]*hv1; }
    }
    const float* ub = U + ((size_t)(b*NN + p0)*MM)*CC;
    #pragma unroll 2
    for (int l = 0; l < MM; ++l) {
        float blv = BlT[l*NN + q];
        const float* ur0 = ub + (size_t)l*CC;           // wave-uniform rows
        const float* ur1 = ur0 + (size_t)MM*CC;
        #pragma unroll
        for (int o = 0; o < CC; ++o) { acc0[o] += ur0[o]*blv; acc1[o] += ur1[o]*blv; }
    }
    #pragma unroll
    for (int o = 0; o < CC; ++o) {
        hb[(size_t)o*PLANE]      = fast_tanh(acc0[o]);
        hb[(size_t)o*PLANE + NN] = fast_tanh(acc1[o]);
    }
}

// ---------------------------------------------------------------------------
// Last layer fused: combine (no tanh) -> fc1 -> tanh -> fc2 -> out. 2 rows/block.
// fc1 i-loop FULLY unrolled (acc[i] must be constant-indexed — round-5 lesson).
__global__ __launch_bounds__(256, 2) void k_combine_fc(const float* __restrict__ h, const float* __restrict__ U,
        const float* __restrict__ BlT, const float* __restrict__ cwt, const float* __restrict__ cb,
        const float* __restrict__ w1, const float* __restrict__ b1,
        const float* __restrict__ w2, const float* __restrict__ b2, float* __restrict__ out) {
    int b = blockIdx.x >> 7, p2 = blockIdx.x & 127;
    int p0 = 2*p2, q = threadIdx.x;
    float acc0[CC], acc1[CC];
    #pragma unroll
    for (int o = 0; o < CC; ++o) { float cv = cb[o]; acc0[o] = cv; acc1[o] = cv; }
    const float* hb = h + (size_t)b*CC*PLANE + (size_t)p0*NN + q;
    #pragma unroll 4
    for (int i = 0; i < CC; ++i) {
        float hv0 = hb[(size_t)i*PLANE];
        float hv1 = hb[(size_t)i*PLANE + NN];
        const float* wr = &cwt[i*CC];                   // wave-uniform -> s_load
        #pragma unroll
        for (int o = 0; o < CC; ++o) { acc0[o] += wr[o]*hv0; acc1[o] += wr[o]*hv1; }
    }
    const float* ub = U + ((size_t)(b*NN + p0)*MM)*CC;
    #pragma unroll 2
    for (int l = 0; l < MM; ++l) {
        float blv = BlT[l*NN + q];
        const float* ur0 = ub + (size_t)l*CC;
        const float* ur1 = ur0 + (size_t)MM*CC;
        #pragma unroll
        for (int o = 0; o < CC; ++o) { acc0[o] += ur0[o]*blv; acc1[o] += ur1[o]*blv; }
    }
    // fc1 -> tanh -> fc2 on the in-register channel vectors (both rows share s_loads)
    float ov0 = b2[0], ov1 = b2[0];
    const int FCH = 8;
    for (int f0 = 0; f0 < FCD; f0 += FCH) {
        float a0[FCH], a1[FCH];
        #pragma unroll
        for (int f = 0; f < FCH; ++f) { float bv = b1[f0+f]; a0[f] = bv; a1[f] = bv; }
        #pragma unroll                                  // FULL unroll: acc[i] constant-indexed
        for (int i = 0; i < CC; ++i) {
            float hv0 = acc0[i], hv1 = acc1[i];
            const float* wr = &w1[i*FCD + f0];          // wave-uniform -> s_load
            #pragma unroll
            for (int f = 0; f < FCH; ++f) { a0[f] += hv0*wr[f]; a1[f] += hv1*wr[f]; }
        }
        #pragma unroll
        for (int f = 0; f < FCH; ++f) {
            float wv = w2[f0+f];
            ov0 += fast_tanh(a0[f]) * wv;
            ov1 += fast_tanh(a1[f]) * wv;
        }
    }
    size_t ob = ((size_t)b*NN + p0)*NN + q;
    out[ob]      = ov0;
    out[ob + NN] = ov1;
}

// ---------------------------------------------------------------------------
extern "C" void kernel_launch(void* const* d_in, const int* in_sizes, int n_in,
                              void* d_out, int out_size, void* d_ws, size_t ws_size,
                              hipStream_t stream) {
    const float* x      = (const float*)d_in[0];
    const float* fc0_w  = (const float*)d_in[1];
    const float* fc0_b  = (const float*)d_in[2];
    const float* sp_w1  = (const float*)d_in[3];
    const float* sp_w2  = (const float*)d_in[4];
    const float* conv_w = (const float*)d_in[5];
    const float* conv_b = (const float*)d_in[6];
    const float* fc1_w  = (const float*)d_in[7];
    const float* fc1_b  = (const float*)d_in[8];
    const float* fc2_w  = (const float*)d_in[9];
    const float* fc2_b  = (const float*)d_in[10];

    float* ws = (float*)d_ws;
    const size_t HSZ = (size_t)BB*CC*PLANE;           // 33,554,432 floats (134.2 MB)
    float* hA  = ws;
    float* Gt  = hA + HSZ;                            // NKK*BB*CC*MM = 409,600
    float* S   = Gt + (size_t)NKK*BB*CC*MM;           // BB*NKK*MM*CC = 409,600
    float* U   = S  + (size_t)BB*NKK*MM*CC;           // BB*NN*MM*CC  = 2,621,440
    float* FlT = U  + (size_t)BB*NN*MM*CC;            // NN*MM   =  5,120
    float* FkT = FlT + NN*MM;                         // NN*NKK  = 10,240
    float* BkT = FkT + NN*NKK;                        // NKK*NN  = 10,240
    float* BlT = BkT + NKK*NN;                        // MM*NN   =  5,120
    float* CwT = BlT + MM*NN;                         // NLAY*CC*CC = 12,288
    // total = 37,038,080 floats = 148.2 MB of workspace

    k_basis<<<1, 256, 0, stream>>>(FlT, FkT, BkT, BlT, CwT, conv_w);
    k_fc0<<<BB*NN, 256, 0, stream>>>(x, fc0_w, fc0_b, hA);

    for (int lay = 0; lay < NLAY; ++lay) {
        const float* w1 = sp_w1 + (size_t)lay*CC*CC*MM*MM;
        const float* w2 = sp_w2 + (size_t)lay*CC*CC*MM*MM;
        k_fwd<<<BB*CC, 256, 0, stream>>>(hA, FkT, FlT, Gt);
        k_spec<<<NKK, 256, BB*CC*MM*sizeof(float), stream>>>(Gt, w1, w2, S);
        k_inv1<<<BB*NN, 256, 0, stream>>>(S, BkT, U);
        if (lay != NLAY-1) {
            k_combine<<<BB*NN/2, 256, 0, stream>>>(
                hA, U, BlT, CwT + lay*CC*CC, conv_b + lay*CC);
        } else {
            k_combine_fc<<<BB*NN/2, 256, 0, stream>>>(
                hA, U, BlT, CwT + lay*CC*CC, conv_b + lay*CC,
                fc1_w, fc1_b, fc2_w, fc2_b, (float*)d_out);
        }
    }
}

// Round 8
// 1056.250 us; speedup vs baseline: 1.2297x; 1.2297x over previous
//
#include <hip/hip_runtime.h>
#include <math.h>

#define BB    8
#define CC    64
#define NN    256
#define MM    20      // retained modes per axis
#define NKK   40      // retained row-modes: {0..19} U {236..255}
#define NLAY  3
#define FCD   128
#define PLANE (NN*NN)

// Fast tanh: clamp + exp-based. v_exp_f32/v_rcp_f32, ~1e-7 abs error, no branches.
__device__ __forceinline__ float fast_tanh(float x) {
    float xc = fminf(fmaxf(x, -15.f), 15.f);
    float e = __expf(2.f * xc);
    return (e - 1.f) / (e + 1.f);
}

// ---------------------------------------------------------------------------
// Basis precompute (double precision on device; tiny).
__global__ __launch_bounds__(256) void k_basis(float* __restrict__ FlT, float* __restrict__ FkT,
                                               float* __restrict__ BkT, float* __restrict__ BlT,
                                               float* __restrict__ CwT, const float* __restrict__ conv_w) {
    int t = threadIdx.x;
    const double PI = 3.14159265358979323846;
    for (int j = t; j < NN*MM; j += 256) {
        int y = j / MM, l = j % MM;
        double g = (y == 0 || y == NN-1) ? 1.0 : 2.0;
        FlT[j] = (float)(g * cos(PI * (double)(l*y) / (double)(NN-1)));
    }
    for (int j = t; j < NN*NKK; j += 256) {
        int x = j / NKK, k = j % NKK;
        int rk = (k < MM) ? k : (NN - NKK + k);
        double g = (x == 0 || x == NN-1) ? 1.0 : 2.0;
        FkT[j] = (float)(g * cos(PI * (double)(rk*x) / (double)(NN-1)));
    }
    for (int j = t; j < NKK*NN; j += 256) {
        int k = j / NN, p = j % NN;
        int rk = (k < MM) ? k : (NN - NKK + k);
        double g = (rk == 0 || rk == NN-1) ? 1.0 : 2.0;
        BkT[j] = (float)(g * cos(PI * (double)(rk*p) / (double)(NN-1)));
    }
    for (int j = t; j < MM*NN; j += 256) {
        int l = j / NN, q = j % NN;
        double g = (l == 0) ? 1.0 : 2.0;
        BlT[j] = (float)(g * cos(PI * (double)(q*l) / (double)(NN-1)));
    }
    for (int j = t; j < NLAY*CC*CC; j += 256) {
        int lay = j / (CC*CC), r = j % (CC*CC);
        int i = r / CC, o = r % CC;
        CwT[j] = conv_w[lay*CC*CC + o*CC + i];
    }
}

// ---------------------------------------------------------------------------
// fc0: h[b,c,p,q] = sum_d x[b,p,q,d]*w[d,c] + bias[c].  Block=(b,p), thread=q.
__global__ __launch_bounds__(256) void k_fc0(const float* __restrict__ xin, const float* __restrict__ w,
                                             const float* __restrict__ bias, float* __restrict__ h) {
    __shared__ float xs[NN*3];
    int b = blockIdx.x >> 8, p = blockIdx.x & 255, q = threadIdx.x;
    size_t rowbase = ((size_t)(b*NN + p)*NN) * 3;
    for (int j = q; j < NN*3; j += 256) xs[j] = xin[rowbase + j];
    __syncthreads();
    float v0 = xs[q*3+0], v1 = xs[q*3+1], v2 = xs[q*3+2];
    size_t obase = (size_t)b*CC*PLANE + (size_t)p*NN + q;
    #pragma unroll 8
    for (int c = 0; c < CC; ++c) {
        float hv = bias[c] + v0*w[c] + v1*w[CC+c] + v2*w[2*CC+c];
        h[obase + (size_t)c*PLANE] = hv;
    }
}

// ---------------------------------------------------------------------------
// Forward truncated DCT: per (b,c) plane, G[k,l] = Fk @ h @ FlT.
__global__ __launch_bounds__(256, 2) void k_fwd(const float* __restrict__ h, const float* __restrict__ FkT,
                                                const float* __restrict__ FlT, float* __restrict__ Gt) {
    __shared__ float P[NKK][NN+1];
    int plane = blockIdx.x;                 // b*CC + c
    int t = threadIdx.x;
    const float* hp = h + (size_t)plane * PLANE;
    float acc[NKK];
    #pragma unroll
    for (int k = 0; k < NKK; ++k) acc[k] = 0.f;
    #pragma unroll 2
    for (int x = 0; x < NN; ++x) {
        float hv = hp[x*NN + t];
        const float* fr = &FkT[x*NKK];      // wave-uniform address -> s_load
        #pragma unroll
        for (int k = 0; k < NKK; ++k) acc[k] += fr[k] * hv;
    }
    #pragma unroll
    for (int k = 0; k < NKK; ++k) P[k][t] = acc[k];
    __syncthreads();
    int b = plane >> 6, c = plane & 63;
    for (int j = t; j < NKK*MM; j += 256) {
        int k = j / MM, l = j % MM;
        float a = 0.f;
        for (int y = 0; y < NN; ++y) a += P[k][y] * FlT[y*MM + l];
        Gt[((size_t)(k*BB + b)*CC + c)*MM + l] = a;
    }
}

// ---------------------------------------------------------------------------
// Spectral mode-mix: S[b,k,l,o] = sum_i G[b,i,kb,l] * w[i,o,kk,l].
// S layout [b][k][l][o] (o contiguous) for coalesced k_inv1 / wave-uniform U rows.
__global__ __launch_bounds__(256, 2) void k_spec(const float* __restrict__ Gt, const float* __restrict__ w1,
                                                 const float* __restrict__ w2, float* __restrict__ S) {
    extern __shared__ float gl[];           // BB*CC*MM = 10240 floats ([b][c][l] order)
    int kb = blockIdx.x;
    int t = threadIdx.x;
    const float* chunk = Gt + (size_t)kb * (BB*CC*MM);
    for (int j = t; j < BB*CC*MM; j += 256) gl[j] = chunk[j];
    __syncthreads();
    int o = t & 63, g = t >> 6;
    int b0 = 2*g, b1 = 2*g + 1;
    const float* wp; int kk;
    if (kb < MM) { wp = w1; kk = kb; } else { wp = w2; kk = kb - MM; }
    float a0[MM], a1[MM];
    #pragma unroll
    for (int l = 0; l < MM; ++l) { a0[l] = 0.f; a1[l] = 0.f; }
    for (int i = 0; i < CC; ++i) {
        const float4* wr4 = reinterpret_cast<const float4*>(wp + ((size_t)(i*CC + o)*MM + kk)*MM);
        const float4* g04 = reinterpret_cast<const float4*>(&gl[(b0*CC + i)*MM]);
        const float4* g14 = reinterpret_cast<const float4*>(&gl[(b1*CC + i)*MM]);
        #pragma unroll
        for (int l4 = 0; l4 < MM/4; ++l4) {
            float4 wv = wr4[l4];
            float4 gv0 = g04[l4];
            float4 gv1 = g14[l4];
            a0[4*l4+0] += wv.x*gv0.x; a0[4*l4+1] += wv.y*gv0.y;
            a0[4*l4+2] += wv.z*gv0.z; a0[4*l4+3] += wv.w*gv0.w;
            a1[4*l4+0] += wv.x*gv1.x; a1[4*l4+1] += wv.y*gv1.y;
            a1[4*l4+2] += wv.z*gv1.z; a1[4*l4+3] += wv.w*gv1.w;
        }
    }
    #pragma unroll
    for (int l = 0; l < MM; ++l) {
        S[((size_t)(b0*NKK + kb)*MM + l)*CC + o] = a0[l];   // coalesced in o
        S[((size_t)(b1*NKK + kb)*MM + l)*CC + o] = a1[l];
    }
}

// ---------------------------------------------------------------------------
// Inverse stage 1: U[b,p,l,o] = sum_k BkT[k,p] * S[b,k,l,o].
// Block=(b,p); wave w handles l = w + 4j (j=0..4); lane = o. No LDS.
__global__ __launch_bounds__(256, 2) void k_inv1(const float* __restrict__ S, const float* __restrict__ BkT,
                                                 float* __restrict__ U) {
    int b = blockIdx.x >> 8, p = blockIdx.x & 255;
    int o = threadIdx.x & 63, w = threadIdx.x >> 6;
    float acc[5];
    #pragma unroll
    for (int j = 0; j < 5; ++j) acc[j] = 0.f;
    for (int k = 0; k < NKK; ++k) {
        float bk = BkT[k*NN + p];                       // wave-uniform
        const float* sb = S + ((size_t)(b*NKK + k)*MM + w)*CC + o;
        #pragma unroll
        for (int j = 0; j < 5; ++j) acc[j] += bk * sb[(size_t)(4*j)*CC];
    }
    float* ub = U + ((size_t)(b*NN + p)*MM + w)*CC + o;
    #pragma unroll
    for (int j = 0; j < 5; ++j) ub[(size_t)(4*j)*CC] = acc[j];
}

// ---------------------------------------------------------------------------
// Combine IN PLACE, ONE row per block, NO LDS:
//   h[b,o,p,q] = tanh( conv(h)[o] + cb[o] + sum_l U[b,p,l,o]*BlT[l,q] )
// Weights/U rows wave-uniform -> scalar pipe. ONE acc[64] per thread —
// round-7 lesson: two 64-float register arrays get demoted to scratch
// (VGPR_Count=80 < live set), one promotes (r6: VGPR=92).
__global__ __launch_bounds__(256, 2) void k_combine(float* h, const float* __restrict__ U,
                                                    const float* __restrict__ BlT, const float* __restrict__ cwt,
                                                    const float* __restrict__ cb) {
    int b = blockIdx.x >> 8, p = blockIdx.x & 255;
    int q = threadIdx.x;
    float acc[CC];
    #pragma unroll
    for (int o = 0; o < CC; ++o) acc[o] = cb[o];
    float* hb = h + (size_t)b*CC*PLANE + (size_t)p*NN + q;
    #pragma unroll 4
    for (int i = 0; i < CC; ++i) {
        float hv = hb[(size_t)i*PLANE];
        const float* wr = &cwt[i*CC];                   // wave-uniform -> s_load
        #pragma unroll
        for (int o = 0; o < CC; ++o) acc[o] += wr[o]*hv;
    }
    const float* ub = U + ((size_t)(b*NN + p)*MM)*CC;
    #pragma unroll 2
    for (int l = 0; l < MM; ++l) {
        float blv = BlT[l*NN + q];
        const float* ur = ub + (size_t)l*CC;            // wave-uniform row
        #pragma unroll
        for (int o = 0; o < CC; ++o) acc[o] += ur[o]*blv;
    }
    #pragma unroll
    for (int o = 0; o < CC; ++o) hb[(size_t)o*PLANE] = fast_tanh(acc[o]);
}

// ---------------------------------------------------------------------------
// Last layer fused: combine (no tanh) -> fc1 -> tanh -> fc2 -> out. 1 row/block.
// fc1 i-loop FULLY unrolled (acc[i] constant-indexed — round-5 lesson);
// single acc[64] + a[8] register shape (round-7 lesson).
__global__ __launch_bounds__(256, 2) void k_combine_fc(const float* __restrict__ h, const float* __restrict__ U,
        const float* __restrict__ BlT, const float* __restrict__ cwt, const float* __restrict__ cb,
        const float* __restrict__ w1, const float* __restrict__ b1,
        const float* __restrict__ w2, const float* __restrict__ b2, float* __restrict__ out) {
    int b = blockIdx.x >> 8, p = blockIdx.x & 255;
    int q = threadIdx.x;
    float acc[CC];
    #pragma unroll
    for (int o = 0; o < CC; ++o) acc[o] = cb[o];
    const float* hb = h + (size_t)b*CC*PLANE + (size_t)p*NN + q;
    #pragma unroll 4
    for (int i = 0; i < CC; ++i) {
        float hv = hb[(size_t)i*PLANE];
        const float* wr = &cwt[i*CC];                   // wave-uniform -> s_load
        #pragma unroll
        for (int o = 0; o < CC; ++o) acc[o] += wr[o]*hv;
    }
    const float* ub = U + ((size_t)(b*NN + p)*MM)*CC;
    #pragma unroll 2
    for (int l = 0; l < MM; ++l) {
        float blv = BlT[l*NN + q];
        const float* ur = ub + (size_t)l*CC;
        #pragma unroll
        for (int o = 0; o < CC; ++o) acc[o] += ur[o]*blv;
    }
    // fc1 -> tanh -> fc2 on the in-register channel vector
    float ov = b2[0];
    const int FCH = 8;
    for (int f0 = 0; f0 < FCD; f0 += FCH) {
        float a[FCH];
        #pragma unroll
        for (int f = 0; f < FCH; ++f) a[f] = b1[f0 + f];
        #pragma unroll                                  // FULL unroll: acc[i] constant-indexed
        for (int i = 0; i < CC; ++i) {
            float hv = acc[i];
            const float* wr = &w1[i*FCD + f0];          // wave-uniform -> s_load
            #pragma unroll
            for (int f = 0; f < FCH; ++f) a[f] += hv*wr[f];
        }
        #pragma unroll
        for (int f = 0; f < FCH; ++f) ov += fast_tanh(a[f]) * w2[f0 + f];
    }
    out[(size_t)blockIdx.x*NN + q] = ov;
}

// ---------------------------------------------------------------------------
extern "C" void kernel_launch(void* const* d_in, const int* in_sizes, int n_in,
                              void* d_out, int out_size, void* d_ws, size_t ws_size,
                              hipStream_t stream) {
    const float* x      = (const float*)d_in[0];
    const float* fc0_w  = (const float*)d_in[1];
    const float* fc0_b  = (const float*)d_in[2];
    const float* sp_w1  = (const float*)d_in[3];
    const float* sp_w2  = (const float*)d_in[4];
    const float* conv_w = (const float*)d_in[5];
    const float* conv_b = (const float*)d_in[6];
    const float* fc1_w  = (const float*)d_in[7];
    const float* fc1_b  = (const float*)d_in[8];
    const float* fc2_w  = (const float*)d_in[9];
    const float* fc2_b  = (const float*)d_in[10];

    float* ws = (float*)d_ws;
    const size_t HSZ = (size_t)BB*CC*PLANE;           // 33,554,432 floats (134.2 MB)
    float* hA  = ws;
    float* Gt  = hA + HSZ;                            // NKK*BB*CC*MM = 409,600
    float* S   = Gt + (size_t)NKK*BB*CC*MM;           // BB*NKK*MM*CC = 409,600
    float* U   = S  + (size_t)BB*NKK*MM*CC;           // BB*NN*MM*CC  = 2,621,440
    float* FlT = U  + (size_t)BB*NN*MM*CC;            // NN*MM   =  5,120
    float* FkT = FlT + NN*MM;                         // NN*NKK  = 10,240
    float* BkT = FkT + NN*NKK;                        // NKK*NN  = 10,240
    float* BlT = BkT + NKK*NN;                        // MM*NN   =  5,120
    float* CwT = BlT + MM*NN;                         // NLAY*CC*CC = 12,288
    // total = 37,038,080 floats = 148.2 MB of workspace

    k_basis<<<1, 256, 0, stream>>>(FlT, FkT, BkT, BlT, CwT, conv_w);
    k_fc0<<<BB*NN, 256, 0, stream>>>(x, fc0_w, fc0_b, hA);

    for (int lay = 0; lay < NLAY; ++lay) {
        const float* w1 = sp_w1 + (size_t)lay*CC*CC*MM*MM;
        const float* w2 = sp_w2 + (size_t)lay*CC*CC*MM*MM;
        k_fwd<<<BB*CC, 256, 0, stream>>>(hA, FkT, FlT, Gt);
        k_spec<<<NKK, 256, BB*CC*MM*sizeof(float), stream>>>(Gt, w1, w2, S);
        k_inv1<<<BB*NN, 256, 0, stream>>>(S, BkT, U);
        if (lay != NLAY-1) {
            k_combine<<<BB*NN, 256, 0, stream>>>(
                hA, U, BlT, CwT + lay*CC*CC, conv_b + lay*CC);
        } else {
            k_combine_fc<<<BB*NN, 256, 0, stream>>>(
                hA, U, BlT, CwT + lay*CC*CC, conv_b + lay*CC,
                fc1_w, fc1_b, fc2_w, fc2_b, (float*)d_out);
        }
    }
}